// Round 6
// baseline (9.729 us; speedup 1.0000x reference)
//
#include <hip/hip_runtime.h>

// QuanvolutionClassifier, closed form + MFMA (R6).
//
// Circuit collapses analytically (theta drops out; see prior rounds):
//   feats per 2x2 patch [a b; c d] = {cos a, cos a cos b, cos c, cos c cos d}
//   out = log_softmax(feats @ W^T + bias)
//
// R6 vs R5:
//  - No W LDS staging / no pre-MFMA barrier: each lane's B-frag is 8
//    contiguous floats of one W row (L2-resident, 16x128B chunks per wave),
//    loaded directly and converted in-register. A-frag zeros cover the k>=784
//    tail, so B needs no masking (only address clamping).
//  - k-loop fully unrolled (4 predicated wave-uniform steps), all x/W loads
//    issued before any compute -> 12-16 loads in flight, one vmcnt drain.
//  - Parallel epilogue: 256 threads = 16 rows x 16 cols, 8 LDS reads each,
//    then shfl_xor max/sum within 16-lane groups for log-softmax.

typedef float f32x4 __attribute__((ext_vector_type(4)));
typedef short s16x8 __attribute__((ext_vector_type(8)));

__device__ __forceinline__ ushort f2bf(float f) {   // f32 -> bf16 RNE
    unsigned u = __float_as_uint(f);
    u += 0x7fffu + ((u >> 16) & 1u);
    return (ushort)(u >> 16);
}

__global__ __launch_bounds__(512) void quanv_mfma(
    const float* __restrict__ x,     // [B, 784]
    const float* __restrict__ W,     // [10, 784]
    const float* __restrict__ bias,  // [10]
    float* __restrict__ out,         // [B, 10]
    int B)
{
    __shared__ float Cp[8][16][16];     // per-wave C partials (8 KB)

    const int tid  = threadIdx.x;
    const int wv   = tid >> 6;          // wave 0..7 (k-split)
    const int lane = tid & 63;
    const int h    = lane >> 4;         // k-subgroup 0..3
    const int col  = lane & 15;         // A: row-in-tile / B: class column
    const int rbase = blockIdx.x << 4;  // 16 batch rows per block

    int r = rbase + col;
    if (r >= B) r = B - 1;
    const float* __restrict__ xr = x + (size_t)r * 784;
    const int colw = col < 10 ? col : 9;              // clamp (values unused)
    const float* __restrict__ wr = W + colw * 784;    // lane's W row

    // ---- issue ALL loads up front (wave-uniform predication on t) ----
    float4 xt[4], xb[4], wa[4], wb[4];
#pragma unroll
    for (int i = 0; i < 4; ++i) {
        const int t = wv + 8 * i;
        if (t < 25) {
            const int p0 = 8 * t + 2 * h;         // lane's first patch
            const bool ok = p0 < 196;             // k >= 784 tail
            const int pp = ok ? p0 : 0;
            const int pr = pp / 14;               // pp even -> pc even
            const int pc = pp - 14 * pr;
            const float4* __restrict__ xp =
                reinterpret_cast<const float4*>(xr + pr * 56 + 2 * pc);
            xt[i] = xp[0];                        // img row 2pr
            xb[i] = xp[7];                        // img row 2pr+1
            const int k0 = ok ? (32 * t + 8 * h) : 0;
            const float4* __restrict__ wp =
                reinterpret_cast<const float4*>(wr + k0);
            wa[i] = wp[0];
            wb[i] = wp[1];
        }
    }

    // ---- compute + MFMA ----
    f32x4 acc = {0.f, 0.f, 0.f, 0.f};
#pragma unroll
    for (int i = 0; i < 4; ++i) {
        const int t = wv + 8 * i;
        if (t < 25) {
            const bool ok = (8 * t + 2 * h) < 196;
            float f0 = __cosf(xt[i].x), f1 = f0 * __cosf(xt[i].y);
            float f2 = __cosf(xb[i].x), f3 = f2 * __cosf(xb[i].y);
            float f4 = __cosf(xt[i].z), f5 = f4 * __cosf(xt[i].w);
            float f6 = __cosf(xb[i].z), f7 = f6 * __cosf(xb[i].w);
            if (!ok) { f0=f1=f2=f3=f4=f5=f6=f7=0.f; }   // zero A-tail
            const s16x8 a = { (short)f2bf(f0), (short)f2bf(f1),
                              (short)f2bf(f2), (short)f2bf(f3),
                              (short)f2bf(f4), (short)f2bf(f5),
                              (short)f2bf(f6), (short)f2bf(f7) };
            const s16x8 b = { (short)f2bf(wa[i].x), (short)f2bf(wa[i].y),
                              (short)f2bf(wa[i].z), (short)f2bf(wa[i].w),
                              (short)f2bf(wb[i].x), (short)f2bf(wb[i].y),
                              (short)f2bf(wb[i].z), (short)f2bf(wb[i].w) };
            acc = __builtin_amdgcn_mfma_f32_16x16x32_bf16(a, b, acc, 0, 0, 0);
        }
    }

    // ---- per-wave partials -> LDS ----
#pragma unroll
    for (int j = 0; j < 4; ++j)
        Cp[wv][(h << 2) + j][col] = acc[j];   // C row = (lane>>4)*4 + j

    __syncthreads();

    // ---- parallel epilogue: 16 rows x 16 cols ----
    if (tid < 256) {
        const int row = tid >> 4;
        const int c   = tid & 15;
        float s = 0.f;
#pragma unroll
        for (int w = 0; w < 8; ++w) s += Cp[w][row][c];
        const bool cv = c < 10;
        const float v = cv ? (s + bias[c]) : -3.0e38f;  // mask garbage cols
        float m = v;
#pragma unroll
        for (int off = 1; off < 16; off <<= 1)
            m = fmaxf(m, __shfl_xor(m, off, 64));       // max within row group
        float e = cv ? __expf(v - m) : 0.f;
#pragma unroll
        for (int off = 1; off < 16; off <<= 1)
            e += __shfl_xor(e, off, 64);                // sum within row group
        const float lse = m + __logf(e);
        const int rr = rbase + row;
        if (cv && rr < B)
            out[(size_t)rr * 10 + c] = v - lse;
    }
}

extern "C" void kernel_launch(void* const* d_in, const int* in_sizes, int n_in,
                              void* d_out, int out_size, void* d_ws, size_t ws_size,
                              hipStream_t stream) {
    const float* x   = (const float*)d_in[0];
    // d_in[1] = theta: provably unused (RZ phases cancel in |amp|^2).
    const float* W   = (const float*)d_in[2];
    const float* b   = (const float*)d_in[3];
    float* out       = (float*)d_out;

    const int B = in_sizes[0] / 784;
    const int blocks = (B + 15) / 16;     // 16 rows per block -> 256 blocks
    quanv_mfma<<<blocks, 512, 0, stream>>>(x, W, b, out, B);
}